// Round 6
// baseline (762.995 us; speedup 1.0000x reference)
//
#include <hip/hip_runtime.h>
#include <stdint.h>

// ThorMoE: per-expert 2-layer MLP.
// E=16, T=512, H=1024, I=4096. fp32 in/out, f16 MFMA compute internally.
// Kernel 1: h[e,t,i] = x @ W1 + b1   (M=512,N=4096,K=1024), BM=128, h->ws f16
// Kernel 2: y[e,t,h] = h @ W2 + b2   (M=512,N=1024,K=4096), BM=64,  y fp32
// BN=128 fixed, BK=32, 256 threads = 4 waves, 16x16x32 MFMA.
//
// R1: conflict-free ds_write_b128 staging (conflicts 7.55e7->1.26e7, 220->183us).
// R3/R4/R5: schedule variants (prefetch/dbuf/raw-barriers) ALL NULL at ~178us.
//   Budget analysis: no pipe >50% (LDS 45%, L2 33%, VALU 17%, MFMA 15%) ->
//   latency-bound, starved of resident waves (K1 ~2.4 blk/CU by 40KB LDS,
//   K2 hard-capped at 2 blk/CU by grid=512).
// R6: concurrency experiment. K1: single 20KB LDS buffer + reg-prefetch +
//   raw lgkm-only barriers -> ~5-6 blocks/CU. K2: BM 128->64 -> grid 1024
//   = 4 blocks/CU. If this nulls, next is the 8-phase 256^2 template.

#define E_ 16
#define T_ 512
#define H_ 1024
#define I_ 4096

typedef _Float16 f16x8 __attribute__((ext_vector_type(8)));
typedef __fp16   h2    __attribute__((ext_vector_type(2)));  // cvt_pkrtz result type
typedef float    f32x4 __attribute__((ext_vector_type(4)));

#define LDK 40  // LDS row stride in f16: 32 + 8 pad (16B-aligned, quad stride 20 mod 32)

// lgkm-only barrier: drains own LDS ops, leaves global prefetch loads in flight.
__device__ __forceinline__ void lds_barrier() {
    __builtin_amdgcn_sched_barrier(0);
    asm volatile("s_waitcnt lgkmcnt(0)" ::: "memory");
    __builtin_amdgcn_sched_barrier(0);
    __builtin_amdgcn_s_barrier();
    __builtin_amdgcn_sched_barrier(0);
}

template <int BM, bool A_IS_F16, bool OUT_IS_F16>
__global__ __launch_bounds__(256, 4) void moe_gemm(const void* __restrict__ Aall,
                                                   const float* __restrict__ Ball,
                                                   const float* __restrict__ biasAll,
                                                   void* __restrict__ Call,
                                                   int M, int N, int K) {
    constexpr int MFRAG = BM / 32;      // m-frags per wave (BM=128 -> 4, 64 -> 2)
    constexpr int AP    = BM / 64;      // A staging passes per thread

    __shared__ _Float16 sA[BM * LDK];   // single buffer
    __shared__ _Float16 sB[128 * LDK];

    const int e   = blockIdx.z;
    const int m0  = blockIdx.y * BM;
    const int n0  = blockIdx.x * 128;
    const int tid = threadIdx.x;
    const int lane = tid & 63;
    const int wave = tid >> 6;
    const int wm = (wave >> 1) * (BM / 2);  // wave row offset in tile
    const int wn = (wave & 1) * 64;         // wave col offset in tile
    const int lrow = lane & 15;             // m (or n) within 16x16 frag
    const int lk8  = (lane >> 4) * 8;       // k offset within frag

    const float* B_e    = Ball + (size_t)e * K * N;
    const float* bias_e = biasAll + (size_t)e * N;
    const float*     A_f32 = (const float*)Aall + (size_t)e * M * K;
    const _Float16*  A_f16 = (const _Float16*)Aall + (size_t)e * M * K;

    // --- staging index precompute ---
    // B: thread owns one n-column (bn) and 16 consecutive k's starting at bkh.
    const int bn  = tid & 127;               // 0..127
    const int bkh = (tid >> 7) * 16;         // 0 or 16
    // A f16: thread owns rows {r + p*64} x 8 k's at c8.
    const int r  = tid >> 2;                 // 0..63
    const int c8 = (tid & 3) * 8;            // 0,8,16,24
    // A f32 (BM=128): rows {ar + p*16} x 8 k's at ak.
    const int ar = (tid >> 6) * 32 + ((tid & 63) >> 2);
    const int ak = (tid & 3) * 8;

    // --- register staging buffers (the in-flight tile) ---
    float bv[16];
    f32x4 a32[2 * AP];
    f16x8 a16[AP];

    auto load_tile = [&](int k0) {
        const float* bsrc = B_e + (size_t)(k0 + bkh) * N + n0 + bn;
#pragma unroll
        for (int kk = 0; kk < 16; ++kk)
            bv[kk] = bsrc[(size_t)kk * N];   // coalesced: lanes = consecutive n
        if (A_IS_F16) {
#pragma unroll
            for (int p = 0; p < AP; ++p)
                a16[p] = *(const f16x8*)(A_f16 + (size_t)(m0 + r + p * 64) * K + k0 + c8);
        } else {
#pragma unroll
            for (int p = 0; p < AP; ++p) {
                const int row = (BM == 128) ? (ar + p * 16) : (tid >> 2);
                const float* a0 = A_f32 + (size_t)(m0 + row) * K + k0 + ak;
                a32[2 * p]     = *(const f32x4*)a0;
                a32[2 * p + 1] = *(const f32x4*)(a0 + 4);
            }
        }
    };

    auto store_tile = [&]() {
        // B: pack 16 k's for column bn, two conflict-free b128 writes.
        f16x8 w0, w1;
#pragma unroll
        for (int j = 0; j < 4; ++j) {
            ((h2*)&w0)[j] = __builtin_amdgcn_cvt_pkrtz(bv[2 * j],     bv[2 * j + 1]);
            ((h2*)&w1)[j] = __builtin_amdgcn_cvt_pkrtz(bv[8 + 2 * j], bv[8 + 2 * j + 1]);
        }
        *(f16x8*)&sB[bn * LDK + bkh]     = w0;
        *(f16x8*)&sB[bn * LDK + bkh + 8] = w1;
        // A
        if (A_IS_F16) {
#pragma unroll
            for (int p = 0; p < AP; ++p)
                *(f16x8*)&sA[(r + p * 64) * LDK + c8] = a16[p];
        } else {
#pragma unroll
            for (int p = 0; p < AP; ++p) {
                const int row = (BM == 128) ? (ar + p * 16) : (tid >> 2);
                f16x8 w;
                ((h2*)&w)[0] = __builtin_amdgcn_cvt_pkrtz(a32[2 * p].x, a32[2 * p].y);
                ((h2*)&w)[1] = __builtin_amdgcn_cvt_pkrtz(a32[2 * p].z, a32[2 * p].w);
                ((h2*)&w)[2] = __builtin_amdgcn_cvt_pkrtz(a32[2 * p + 1].x, a32[2 * p + 1].y);
                ((h2*)&w)[3] = __builtin_amdgcn_cvt_pkrtz(a32[2 * p + 1].z, a32[2 * p + 1].w);
                *(f16x8*)&sA[row * LDK + ak] = w;
            }
        }
    };

    f32x4 acc[MFRAG][4];
    const f32x4 zero = {0.f, 0.f, 0.f, 0.f};
#pragma unroll
    for (int i = 0; i < MFRAG; ++i)
#pragma unroll
        for (int j = 0; j < 4; ++j) acc[i][j] = zero;

    const int nt = K / 32;

    // ---- prologue: tile 0 staged; tile 1 loads in flight ----
    load_tile(0);
    store_tile();
    load_tile(32);
    lds_barrier();

    for (int t = 0; t < nt; ++t) {
        // ---- fragment reads + MFMA on tile t (in the single buffer) ----
        f16x8 af[MFRAG], bf[4];
#pragma unroll
        for (int mi = 0; mi < MFRAG; ++mi)
            af[mi] = *(const f16x8*)&sA[(wm + mi * 16 + lrow) * LDK + lk8];
#pragma unroll
        for (int ni = 0; ni < 4; ++ni)
            bf[ni] = *(const f16x8*)&sB[(wn + ni * 16 + lrow) * LDK + lk8];
#pragma unroll
        for (int mi = 0; mi < MFRAG; ++mi)
#pragma unroll
            for (int ni = 0; ni < 4; ++ni)
                acc[mi][ni] = __builtin_amdgcn_mfma_f32_16x16x32_f16(af[mi], bf[ni], acc[mi][ni], 0, 0, 0);

        // barrier 1: all waves' LDS reads of tile t complete
        lds_barrier();

        if (t + 1 < nt) {
            store_tile();                 // tile t+1 regs -> LDS (counted vmcnt)
            if (t + 2 < nt)
                load_tile((t + 2) * 32);  // issue tile t+2; stays in flight
            // barrier 2: tile t+1 writes visible
            lds_barrier();
        }
    }

    // ---- epilogue: C/D layout col=lane&15, row=(lane>>4)*4+reg (verified m89/m91) ----
    const int row_base = (lane >> 4) * 4;
#pragma unroll
    for (int ni = 0; ni < 4; ++ni) {
        const int n = n0 + wn + ni * 16 + lrow;
        const float bvx = bias_e[n];
#pragma unroll
        for (int mi = 0; mi < MFRAG; ++mi) {
            const int mbase = m0 + wm + mi * 16 + row_base;
#pragma unroll
            for (int rr = 0; rr < 4; ++rr) {
                const float val = acc[mi][ni][rr] + bvx;
                const size_t idx = (size_t)e * M * N + (size_t)(mbase + rr) * N + n;
                if (OUT_IS_F16)
                    ((_Float16*)Call)[idx] = (_Float16)val;
                else
                    ((float*)Call)[idx] = val;
            }
        }
    }
}

extern "C" void kernel_launch(void* const* d_in, const int* in_sizes, int n_in,
                              void* d_out, int out_size, void* d_ws, size_t ws_size,
                              hipStream_t stream) {
    (void)in_sizes; (void)n_in; (void)out_size; (void)ws_size;
    const float* x  = (const float*)d_in[0];  // (E,T,H)
    const float* W1 = (const float*)d_in[1];  // (E,H,I)
    const float* b1 = (const float*)d_in[2];  // (E,I)
    const float* W2 = (const float*)d_in[3];  // (E,I,H)
    const float* b2 = (const float*)d_in[4];  // (E,H)
    float* out = (float*)d_out;               // (E*T, H) fp32
    _Float16* hbuf = (_Float16*)d_ws;         // (E,T,I) f16 intermediate, 67.1 MB

    dim3 blk(256, 1, 1);
    dim3 g1(I_ / 128, T_ / 128, E_);  // 32 x 4 x 16 = 2048 blocks, BM=128
    moe_gemm<128, false, true><<<g1, blk, 0, stream>>>((const void*)x, W1, b1, (void*)hbuf, T_, I_, H_);
    dim3 g2(H_ / 128, T_ / 64, E_);   // 8 x 8 x 16 = 1024 blocks, BM=64
    moe_gemm<64, true, false><<<g2, blk, 0, stream>>>((const void*)hbuf, W2, b2, (void*)out, T_, H_, I_);
}